// Round 7
// baseline (295.474 us; speedup 1.0000x reference)
//
#include <hip/hip_runtime.h>
#include <cstdint>

// Problem constants (from reference)
#define BB 32
#define TV 8192
#define KK 64
#define TS 128
#define MARGIN_F 0.1f
#define LAMBDA_F 0.5f

static constexpr int KSTR = BB * TV;     // pred_intervened stride per k (floats)
static constexpr int GPB = TV / 32;      // 256 half-groups (32 rows) per batch
static constexpr int NG = BB * GPB;      // 8192 half-groups total

// Workspace layout (bytes):
//   acc   @ 0      : 1 float
//   len   @ 64     : 32 ints (valid count per b)
//   wsV   @ 4096   : u32[8192]      bit r = valid(row 32g+r)          (32 KB)
//   wsA   @ 65536  : u32[8192][64]  [g][k] bit r = aligned&valid      (2 MB)
static constexpr size_t ACC_OFF = 0;
static constexpr size_t LEN_OFF = 64;
static constexpr size_t WSV_OFF = 4096;
static constexpr size_t WSA_OFF = 65536;

// ---------------------------------------------------------------------------
// Pack, gather-style — NO BALLOTS in the gt loop (R4/R5/R6 all plateaued at
// ~86us because __ballot is convergent: the compiler refuses to pipeline
// loads across it, serializing every batch on full memory latency).
// Lane k loads its own column gt[r][idx[k]] per row: all 64 lane addresses
// of one instruction lie in ONE 512 B row (8 cache lines), so gt still
// streams through HBM exactly once, but the per-lane chain is pure
// load->cmp->or with 8 independent loads per unroll batch. Zero LDS, low
// VGPR -> 32 waves/CU. Invalid half-groups skip the gt stream (~25%).
// Semantics identical to the absmax-0.0 rounds: bit j = gt[r0+j][c]>0, &V.
// ---------------------------------------------------------------------------
__global__ __launch_bounds__(256) void pack_kernel(
    const int* __restrict__ gt, const int* __restrict__ mv,
    const int* __restrict__ idx,
    unsigned int* __restrict__ wsA, unsigned int* __restrict__ wsV,
    int* __restrict__ len) {
  const int lane = threadIdx.x & 63;
  const int g = blockIdx.x * 4 + (threadIdx.x >> 6);   // half-group id 0..8191
  const int r0 = g * 32;
  const int b = g >> 8;                                // GPB = 256
  const int c = idx[lane];                             // lane == k

  // validity of rows r0..r0+31 (lanes 32..63 duplicate; take low 32 bits).
  // One ballot per group, OUTSIDE the hot loop.
  const unsigned int V = (unsigned int)__ballot(mv[r0 + (lane & 31)] != 0);
  if (lane == 0) {
    wsV[g] = V;
    if (V) atomicAdd(&len[b], __popc(V));
  }

  unsigned int plane = 0u;
  if (V != 0u) {
    const int* gp = gt + (size_t)r0 * TS + c;          // my column, row r0
#pragma unroll
    for (int j = 0; j < 32; j += 8) {
      const int x0 = gp[(j + 0) * TS];
      const int x1 = gp[(j + 1) * TS];
      const int x2 = gp[(j + 2) * TS];
      const int x3 = gp[(j + 3) * TS];
      const int x4 = gp[(j + 4) * TS];
      const int x5 = gp[(j + 5) * TS];
      const int x6 = gp[(j + 6) * TS];
      const int x7 = gp[(j + 7) * TS];
      plane |= (unsigned int)(x0 > 0) << (j + 0);
      plane |= (unsigned int)(x1 > 0) << (j + 1);
      plane |= (unsigned int)(x2 > 0) << (j + 2);
      plane |= (unsigned int)(x3 > 0) << (j + 3);
      plane |= (unsigned int)(x4 > 0) << (j + 4);
      plane |= (unsigned int)(x5 > 0) << (j + 5);
      plane |= (unsigned int)(x6 > 0) << (j + 6);
      plane |= (unsigned int)(x7 > 0) << (j + 7);
    }
    plane &= V;                                        // aligned requires valid
  }
  wsA[(size_t)g * 64 + lane] = plane;                  // coalesced 256 B/wave
}

// ---------------------------------------------------------------------------
// Main: one block per (k,b), 2048 blocks, 2 KB LDS -> 32 waves/CU. 8 elems
// per thread per iter (4 independent global float4 loads in flight). Masks
// from LDS u32 words (8-lane same-address broadcast: conflict-free). No
// cross-lane ops until ONE per-block epilogue; one atomicAdd per block.
// Epilogue algebra verified absmax-0.0 since R2 (cn = len - ca).
// ---------------------------------------------------------------------------
__global__ __launch_bounds__(256) void main_kernel(
    const float* __restrict__ po, const float* __restrict__ pi,
    const unsigned int* __restrict__ wsA, const unsigned int* __restrict__ wsV,
    const int* __restrict__ len, float* __restrict__ acc) {
  const int k = blockIdx.x & (KK - 1);
  const int b = blockIdx.x >> 6;
  const int tid = threadIdx.x;

  __shared__ unsigned int sA[GPB];   // my k's plane words for this b
  __shared__ unsigned int sV[GPB];
  sA[tid] = wsA[(size_t)(b * GPB + tid) * 64 + k];
  sV[tid] = wsV[b * GPB + tid];
  __syncthreads();

  const float* pob = po + (size_t)b * TV;
  const float* pik = pi + (size_t)k * KSTR + (size_t)b * TV;
  const int L = len[b];                        // prefix length, >= TV/2
  const int Tlim = (L + 2047) & ~2047;         // granularity 256 thr * 8 elem

  float sa = 0.f, sv = 0.f;
  int ca = 0;
  for (int t0 = tid * 8; t0 < Tlim; t0 += 2048) {
    const float4 xo0 = *(const float4*)(pob + t0);
    const float4 xo1 = *(const float4*)(pob + t0 + 4);
    const float4 xi0 = *(const float4*)(pik + t0);
    const float4 xi1 = *(const float4*)(pik + t0 + 4);
    const unsigned ab = (sA[t0 >> 5] >> (t0 & 31)) & 255u;
    const unsigned vb = (sV[t0 >> 5] >> (t0 & 31)) & 255u;
    {
      const float e = fabsf(__fdividef(1.f, 1.f + __expf(-xo0.x)) -
                            __fdividef(1.f, 1.f + __expf(-xi0.x)));
      if (ab & 1u) sa += e;
      if (vb & 1u) sv += e;
    }
    {
      const float e = fabsf(__fdividef(1.f, 1.f + __expf(-xo0.y)) -
                            __fdividef(1.f, 1.f + __expf(-xi0.y)));
      if (ab & 2u) sa += e;
      if (vb & 2u) sv += e;
    }
    {
      const float e = fabsf(__fdividef(1.f, 1.f + __expf(-xo0.z)) -
                            __fdividef(1.f, 1.f + __expf(-xi0.z)));
      if (ab & 4u) sa += e;
      if (vb & 4u) sv += e;
    }
    {
      const float e = fabsf(__fdividef(1.f, 1.f + __expf(-xo0.w)) -
                            __fdividef(1.f, 1.f + __expf(-xi0.w)));
      if (ab & 8u) sa += e;
      if (vb & 8u) sv += e;
    }
    {
      const float e = fabsf(__fdividef(1.f, 1.f + __expf(-xo1.x)) -
                            __fdividef(1.f, 1.f + __expf(-xi1.x)));
      if (ab & 16u) sa += e;
      if (vb & 16u) sv += e;
    }
    {
      const float e = fabsf(__fdividef(1.f, 1.f + __expf(-xo1.y)) -
                            __fdividef(1.f, 1.f + __expf(-xi1.y)));
      if (ab & 32u) sa += e;
      if (vb & 32u) sv += e;
    }
    {
      const float e = fabsf(__fdividef(1.f, 1.f + __expf(-xo1.z)) -
                            __fdividef(1.f, 1.f + __expf(-xi1.z)));
      if (ab & 64u) sa += e;
      if (vb & 64u) sv += e;
    }
    {
      const float e = fabsf(__fdividef(1.f, 1.f + __expf(-xo1.w)) -
                            __fdividef(1.f, 1.f + __expf(-xi1.w)));
      if (ab & 128u) sa += e;
      if (vb & 128u) sv += e;
    }
    ca += __popc(ab);
  }

  // epilogue: one block reduction, one atomic
  float fca = (float)ca;
#pragma unroll
  for (int off = 32; off > 0; off >>= 1) {
    sa += __shfl_down(sa, off);
    sv += __shfl_down(sv, off);
    fca += __shfl_down(fca, off);
  }
  __shared__ float p0[4], p1[4], p2[4];
  const int w = tid >> 6;
  if ((tid & 63) == 0) { p0[w] = sa; p1[w] = sv; p2[w] = fca; }
  __syncthreads();
  if (tid == 0) {
    const float SA = p0[0] + p0[1] + p0[2] + p0[3];
    const float SV = p1[0] + p1[1] + p1[2] + p1[3];
    const float CA = p2[0] + p2[1] + p2[2] + p2[3];
    const float CN = (float)L - CA;            // aligned is subset of valid
    float pp = 0.f;
    if (CA > 0.f && CN > 0.f) {
      const float d = MARGIN_F - (SA / CA - (SV - SA) / CN);
      pp = d > 0.f ? d : 0.f;
    }
    atomicAdd(acc, pp);
  }
}

__global__ void fin_kernel(const float* __restrict__ acc, float* __restrict__ out) {
  const float ac = acc[0] * (1.0f / (float)(KK * BB));
  out[0] = ac;
  out[1] = ac * LAMBDA_F;
}

extern "C" void kernel_launch(void* const* d_in, const int* in_sizes, int n_in,
                              void* d_out, int out_size, void* d_ws, size_t ws_size,
                              hipStream_t stream) {
  const float* pred_orig = (const float*)d_in[0];   // [B,TV] fp32
  const float* pred_int  = (const float*)d_in[1];   // [K,B,TV] fp32
  const int*   idx       = (const int*)d_in[2];     // [K] int32
  const int*   gt        = (const int*)d_in[3];     // [B,TV,TS] int32
  const int*   mv        = (const int*)d_in[4];     // [B,TV] int32
  float* out = (float*)d_out;

  char* ws = (char*)d_ws;
  float* acc = (float*)(ws + ACC_OFF);
  int* len = (int*)(ws + LEN_OFF);
  unsigned int* wsV = (unsigned int*)(ws + WSV_OFF);
  unsigned int* wsA = (unsigned int*)(ws + WSA_OFF);

  hipMemsetAsync(ws, 0, 192, stream);   // acc + len (ws re-poisoned each call)
  pack_kernel<<<NG / 4, 256, 0, stream>>>(gt, mv, idx, wsA, wsV, len);
  main_kernel<<<BB * KK, 256, 0, stream>>>(pred_orig, pred_int, wsA, wsV, len, acc);
  fin_kernel<<<1, 1, 0, stream>>>(acc, out);
}

// Round 8
// 282.027 us; speedup vs baseline: 1.0477x; 1.0477x over previous
//
#include <hip/hip_runtime.h>
#include <cstdint>

// Problem constants (from reference)
#define BB 32
#define TV 8192
#define KK 64
#define TS 128
#define MARGIN_F 0.1f
#define LAMBDA_F 0.5f

static constexpr int KSTR = BB * TV;     // pred_intervened stride per k (floats)
static constexpr int GPB = TV / 32;      // 256 half-groups (32 rows) per batch
static constexpr int NG = BB * GPB;      // 8192 half-groups total

// Workspace layout (bytes):
//   acc   @ 0      : 1 float
//   len   @ 64     : 32 ints (valid count per b)
//   wsV   @ 4096   : u32[8192]      bit r = valid(row 32g+r)          (32 KB)
//   wsA   @ 65536  : u32[8192][64]  [g][k] bit r = aligned&valid      (2 MB)
static constexpr size_t ACC_OFF = 0;
static constexpr size_t LEN_OFF = 64;
static constexpr size_t WSV_OFF = 4096;
static constexpr size_t WSA_OFF = 65536;

// ---------------------------------------------------------------------------
// Pack, LDS-staged — gt is now read with the EXACT pattern of the 6.3 TB/s
// copy microbenchmark: dwordx4 per lane, stride-1 across the wave, 8
// independent loads in flight, no convergent consumer (R4-R7 all plateaued
// at ~1.2-1.8 TB/s with ballot- or gather-based gt consumption; VALUBusy
// 1.6% in R7 = pure memory wait). Staging: 16 rows (8 KB) per batch into
// this wave's private LDS buffer (ds_write_b128 lane-linear, conflict-free),
// then column-extract via per-lane ds_read_b32 gather (bank = c mod 32,
// ~2 lanes/bank avg = free per m136). No __syncthreads: wave-private buffer.
// Semantics identical to the absmax-0.0 rounds: bit j = gt[r0+j][c]>0, &V.
// ---------------------------------------------------------------------------
__global__ __launch_bounds__(256) void pack_kernel(
    const int* __restrict__ gt, const int* __restrict__ mv,
    const int* __restrict__ idx,
    unsigned int* __restrict__ wsA, unsigned int* __restrict__ wsV,
    int* __restrict__ len) {
  const int lane = threadIdx.x & 63;
  const int w = threadIdx.x >> 6;
  const int g = blockIdx.x * 4 + w;                    // half-group id 0..8191
  const int r0 = g * 32;
  const int b = g >> 8;                                // GPB = 256
  const int c = idx[lane];                             // lane == k

  __shared__ int4 stage[4][512];                       // 8 KB per wave, private
  int4* st = stage[w];
  const int* sw = (const int*)st;

  // one ballot per wave, outside the hot loop (rows r0..r0+31 validity)
  const unsigned int V = (unsigned int)__ballot(mv[r0 + (lane & 31)] != 0);
  if (lane == 0) {
    wsV[g] = V;
    if (V) atomicAdd(&len[b], __popc(V));
  }

  unsigned int plane = 0u;
  if (V != 0u) {
#pragma unroll
    for (int half = 0; half < 2; ++half) {
      // ---- stage 16 rows = 8192 B: 8 independent dwordx4 loads per lane ----
      const int4* gp = (const int4*)(gt + (size_t)(r0 + half * 16) * TS);
      const int4 v0 = gp[0 * 64 + lane];
      const int4 v1 = gp[1 * 64 + lane];
      const int4 v2 = gp[2 * 64 + lane];
      const int4 v3 = gp[3 * 64 + lane];
      const int4 v4 = gp[4 * 64 + lane];
      const int4 v5 = gp[5 * 64 + lane];
      const int4 v6 = gp[6 * 64 + lane];
      const int4 v7 = gp[7 * 64 + lane];
      st[0 * 64 + lane] = v0;
      st[1 * 64 + lane] = v1;
      st[2 * 64 + lane] = v2;
      st[3 * 64 + lane] = v3;
      st[4 * 64 + lane] = v4;
      st[5 * 64 + lane] = v5;
      st[6 * 64 + lane] = v6;
      st[7 * 64 + lane] = v7;
      // ---- extract my column c from the 16 staged rows ----
#pragma unroll
      for (int r = 0; r < 16; ++r) {
        plane |= (unsigned int)(sw[r * TS + c] > 0) << (half * 16 + r);
      }
    }
    plane &= V;                                        // aligned requires valid
  }
  wsA[(size_t)g * 64 + lane] = plane;                  // coalesced 256 B/wave
}

// ---------------------------------------------------------------------------
// Main: UNCHANGED from R7 (clean attribution of the pack delta). One block
// per (k,b), 2 KB LDS, 8 elems/thread/iter, one atomicAdd per block.
// ---------------------------------------------------------------------------
__global__ __launch_bounds__(256) void main_kernel(
    const float* __restrict__ po, const float* __restrict__ pi,
    const unsigned int* __restrict__ wsA, const unsigned int* __restrict__ wsV,
    const int* __restrict__ len, float* __restrict__ acc) {
  const int k = blockIdx.x & (KK - 1);
  const int b = blockIdx.x >> 6;
  const int tid = threadIdx.x;

  __shared__ unsigned int sA[GPB];   // my k's plane words for this b
  __shared__ unsigned int sV[GPB];
  sA[tid] = wsA[(size_t)(b * GPB + tid) * 64 + k];
  sV[tid] = wsV[b * GPB + tid];
  __syncthreads();

  const float* pob = po + (size_t)b * TV;
  const float* pik = pi + (size_t)k * KSTR + (size_t)b * TV;
  const int L = len[b];                        // prefix length, >= TV/2
  const int Tlim = (L + 2047) & ~2047;         // granularity 256 thr * 8 elem

  float sa = 0.f, sv = 0.f;
  int ca = 0;
  for (int t0 = tid * 8; t0 < Tlim; t0 += 2048) {
    const float4 xo0 = *(const float4*)(pob + t0);
    const float4 xo1 = *(const float4*)(pob + t0 + 4);
    const float4 xi0 = *(const float4*)(pik + t0);
    const float4 xi1 = *(const float4*)(pik + t0 + 4);
    const unsigned ab = (sA[t0 >> 5] >> (t0 & 31)) & 255u;
    const unsigned vb = (sV[t0 >> 5] >> (t0 & 31)) & 255u;
    {
      const float e = fabsf(__fdividef(1.f, 1.f + __expf(-xo0.x)) -
                            __fdividef(1.f, 1.f + __expf(-xi0.x)));
      if (ab & 1u) sa += e;
      if (vb & 1u) sv += e;
    }
    {
      const float e = fabsf(__fdividef(1.f, 1.f + __expf(-xo0.y)) -
                            __fdividef(1.f, 1.f + __expf(-xi0.y)));
      if (ab & 2u) sa += e;
      if (vb & 2u) sv += e;
    }
    {
      const float e = fabsf(__fdividef(1.f, 1.f + __expf(-xo0.z)) -
                            __fdividef(1.f, 1.f + __expf(-xi0.z)));
      if (ab & 4u) sa += e;
      if (vb & 4u) sv += e;
    }
    {
      const float e = fabsf(__fdividef(1.f, 1.f + __expf(-xo0.w)) -
                            __fdividef(1.f, 1.f + __expf(-xi0.w)));
      if (ab & 8u) sa += e;
      if (vb & 8u) sv += e;
    }
    {
      const float e = fabsf(__fdividef(1.f, 1.f + __expf(-xo1.x)) -
                            __fdividef(1.f, 1.f + __expf(-xi1.x)));
      if (ab & 16u) sa += e;
      if (vb & 16u) sv += e;
    }
    {
      const float e = fabsf(__fdividef(1.f, 1.f + __expf(-xo1.y)) -
                            __fdividef(1.f, 1.f + __expf(-xi1.y)));
      if (ab & 32u) sa += e;
      if (vb & 32u) sv += e;
    }
    {
      const float e = fabsf(__fdividef(1.f, 1.f + __expf(-xo1.z)) -
                            __fdividef(1.f, 1.f + __expf(-xi1.z)));
      if (ab & 64u) sa += e;
      if (vb & 64u) sv += e;
    }
    {
      const float e = fabsf(__fdividef(1.f, 1.f + __expf(-xo1.w)) -
                            __fdividef(1.f, 1.f + __expf(-xi1.w)));
      if (ab & 128u) sa += e;
      if (vb & 128u) sv += e;
    }
    ca += __popc(ab);
  }

  // epilogue: one block reduction, one atomic
  float fca = (float)ca;
#pragma unroll
  for (int off = 32; off > 0; off >>= 1) {
    sa += __shfl_down(sa, off);
    sv += __shfl_down(sv, off);
    fca += __shfl_down(fca, off);
  }
  __shared__ float p0[4], p1[4], p2[4];
  const int w = tid >> 6;
  if ((tid & 63) == 0) { p0[w] = sa; p1[w] = sv; p2[w] = fca; }
  __syncthreads();
  if (tid == 0) {
    const float SA = p0[0] + p0[1] + p0[2] + p0[3];
    const float SV = p1[0] + p1[1] + p1[2] + p1[3];
    const float CA = p2[0] + p2[1] + p2[2] + p2[3];
    const float CN = (float)L - CA;            // aligned is subset of valid
    float pp = 0.f;
    if (CA > 0.f && CN > 0.f) {
      const float d = MARGIN_F - (SA / CA - (SV - SA) / CN);
      pp = d > 0.f ? d : 0.f;
    }
    atomicAdd(acc, pp);
  }
}

__global__ void fin_kernel(const float* __restrict__ acc, float* __restrict__ out) {
  const float ac = acc[0] * (1.0f / (float)(KK * BB));
  out[0] = ac;
  out[1] = ac * LAMBDA_F;
}

extern "C" void kernel_launch(void* const* d_in, const int* in_sizes, int n_in,
                              void* d_out, int out_size, void* d_ws, size_t ws_size,
                              hipStream_t stream) {
  const float* pred_orig = (const float*)d_in[0];   // [B,TV] fp32
  const float* pred_int  = (const float*)d_in[1];   // [K,B,TV] fp32
  const int*   idx       = (const int*)d_in[2];     // [K] int32
  const int*   gt        = (const int*)d_in[3];     // [B,TV,TS] int32
  const int*   mv        = (const int*)d_in[4];     // [B,TV] int32
  float* out = (float*)d_out;

  char* ws = (char*)d_ws;
  float* acc = (float*)(ws + ACC_OFF);
  int* len = (int*)(ws + LEN_OFF);
  unsigned int* wsV = (unsigned int*)(ws + WSV_OFF);
  unsigned int* wsA = (unsigned int*)(ws + WSA_OFF);

  hipMemsetAsync(ws, 0, 192, stream);   // acc + len (ws re-poisoned each call)
  pack_kernel<<<NG / 4, 256, 0, stream>>>(gt, mv, idx, wsA, wsV, len);
  main_kernel<<<BB * KK, 256, 0, stream>>>(pred_orig, pred_int, wsA, wsV, len, acc);
  fin_kernel<<<1, 1, 0, stream>>>(acc, out);
}

// Round 9
// 269.850 us; speedup vs baseline: 1.0950x; 1.0451x over previous
//
#include <hip/hip_runtime.h>
#include <cstdint>

// Problem constants (from reference)
#define BB 32
#define TV 8192
#define KK 64
#define TS 128
#define MARGIN_F 0.1f
#define LAMBDA_F 0.5f

#define TT 256                                 // t-tile
static constexpr int KSTR = BB * TV;           // pred_intervened stride per k
static constexpr int NTILE = TV / TT;          // 32 tiles per batch

// Workspace (floats, contiguous so one memset covers):
//   gsa[KK*BB] : sum(eff*aligned) per (k,b)
//   gsv[KK*BB] : sum(eff*valid)   per (k,b)
//   gca[KK*BB] : count(aligned)   per (k,b)
//   len[BB]    : count(valid)     per b (int)
// en = (gsv-gsa)/(len-gca)  (aligned is a subset of valid).

__device__ __forceinline__ float sigf(float x) {
  return __fdividef(1.f, 1.f + __expf(-x));
}

// ---------------------------------------------------------------------------
// Software-pipelined fused kernel. Block = (b, tile pair {ti, ti+16}).
// R4-R8 post-mortems: every gt consumer placed in the same loop body as its
// loads drains vmcnt each iteration -> 1.2-1.8 TB/s wall regardless of
// structure/occupancy. Fix: displace consumers one full stage behind issues.
//   prologue: pack tile0 (t<4096, always valid: len>=TV/2) with a depth-2
//             chunk pipeline (chunk = 8 int4 = 16 rows).
//   steady:   4 stages; stage j issues pi k-group j+1 (tile0) AND gt chunk
//             j+1 (tile1), then consumes pi group j (procB) and gt chunk j
//             (ballots -> plane1). Two independent streams overlap; ~12 KB
//             in flight per wave at all times.
//   tile1 B:  pi depth-1 pipeline (no pack left to interleave).
// Planes never leave the block (no 2 MB wsA round-trip). Bit logic verbatim
// from the absmax-0.0 rounds; R4-proven LDS-slab epilogue, 3 atomics per k.
// ---------------------------------------------------------------------------
__global__ __launch_bounds__(256, 2) void fused_kernel(
    const float* __restrict__ po, const float* __restrict__ pi,
    const int* __restrict__ idx, const int* __restrict__ gt,
    const int* __restrict__ mv,
    float* __restrict__ gsa, float* __restrict__ gsv,
    float* __restrict__ gca, int* __restrict__ len) {
  const int tid = threadIdx.x;
  const int lane = tid & 63;
  const int w = tid >> 6;
  const int b = blockIdx.x >> 4;               // 512 blocks: b = bi/16
  const int ti0 = blockIdx.x & 15;             // tiles {ti0, ti0+16}
  const int t0[2] = {ti0 * TT, (ti0 + 16) * TT};

  __shared__ unsigned long long planes[2][4][65];  // [tile][group][k]
  __shared__ unsigned long long sVg[2][4];
  __shared__ float so_s[2][TT];
  __shared__ float saL[KK][65];                // per-(k,lane) partials
  __shared__ float svL[KK][65];

  const int c = idx[lane];                     // lane extracts column for k=lane
  const int csel = c & 3, csh = c >> 2;

  // ---- validity + sigmoid(pred_orig) for both tiles ----
  unsigned long long Vw[2];
#pragma unroll
  for (int i = 0; i < 2; ++i) {
    const int rr = b * TV + t0[i] + w * 64;
    Vw[i] = __ballot(mv[rr + lane] != 0);
    if (lane == 0) {
      sVg[i][w] = Vw[i];
      if (Vw[i]) atomicAdd(&len[b], (int)__popcll(Vw[i]));
    }
    so_s[i][tid] = sigf(po[b * TV + t0[i] + tid]);
  }
  __syncthreads();
  const bool t1v = (sVg[1][0] | sVg[1][1] | sVg[1][2] | sVg[1][3]) != 0ull;

  const int g = lane >> 4;                     // (lane*4)>>6
  const int sh4 = (lane & 15) * 4;             // (lane*4)&63
  float4 so4[2];
  unsigned vb4[2];
#pragma unroll
  for (int i = 0; i < 2; ++i) {
    so4[i] = *(const float4*)&so_s[i][lane * 4];
    vb4[i] = (unsigned)((sVg[i][g] >> sh4) & 15ull);
  }

  // ballot-transpose of one int4 (2 rows) into a plane accumulator.
  // row mapping verbatim from the absmax-0.0 rounds.
  auto procA = [&](int4 v, int r2, unsigned long long& pl) {
    unsigned long long b0 = __ballot(v.x > 0);
    unsigned long long b1 = __ballot(v.y > 0);
    unsigned long long b2 = __ballot(v.z > 0);
    unsigned long long b3 = __ballot(v.w > 0);
    unsigned long long sel =
        (csel == 0) ? b0 : (csel == 1) ? b1 : (csel == 2) ? b2 : b3;
    pl |= ((sel >> csh) & 1ull) << r2;
    pl |= ((sel >> (32 + csh)) & 1ull) << (r2 + 1);
  };

  // ---- prologue: pack tile0, depth-2 chunk pipeline ----
  const int4* g0p = (const int4*)(gt + (size_t)(b * TV + t0[0] + w * 64) * TS) + lane;
  unsigned long long plane0 = 0ull;
  {
    int4 X[8], Y[8];
#pragma unroll
    for (int q = 0; q < 8; ++q) X[q] = g0p[q * 64];           // chunk0
#pragma unroll
    for (int q = 0; q < 8; ++q) Y[q] = g0p[(8 + q) * 64];     // chunk1
#pragma unroll
    for (int q = 0; q < 8; ++q) procA(X[q], 0 * 16 + 2 * q, plane0);
#pragma unroll
    for (int q = 0; q < 8; ++q) X[q] = g0p[(16 + q) * 64];    // chunk2
#pragma unroll
    for (int q = 0; q < 8; ++q) procA(Y[q], 1 * 16 + 2 * q, plane0);
#pragma unroll
    for (int q = 0; q < 8; ++q) Y[q] = g0p[(24 + q) * 64];    // chunk3
#pragma unroll
    for (int q = 0; q < 8; ++q) procA(X[q], 2 * 16 + 2 * q, plane0);
#pragma unroll
    for (int q = 0; q < 8; ++q) procA(Y[q], 3 * 16 + 2 * q, plane0);
  }
  plane0 &= Vw[0];
  planes[0][w][lane] = plane0;
  __syncthreads();

  // ---- steady state: B(tile0) k-groups 1:1 with pack(tile1) chunks ----
  float sa[16], sv[16];
#pragma unroll
  for (int q = 0; q < 16; ++q) { sa[q] = 0.f; sv[q] = 0.f; }

  const float* pib[2] = {pi + (size_t)b * TV + t0[0] + lane * 4,
                         pi + (size_t)b * TV + t0[1] + lane * 4};

  auto issueP = [&](float4 (&Q)[4], int grp, int i) {
#pragma unroll
    for (int q = 0; q < 4; ++q)
      Q[q] = *(const float4*)(pib[i] + (size_t)(16 * w + grp * 4 + q) * KSTR);
  };
  auto procBgrp = [&](float4 (&Q)[4], int grp, int i) {
#pragma unroll
    for (int q = 0; q < 4; ++q) {
      const int kk = grp * 4 + q;
      const int k = 16 * w + kk;
      const unsigned ab4 = (unsigned)((planes[i][g][k] >> sh4) & 15ull);
      const float4 xi = Q[q];
      float e;
      e = fabsf(so4[i].x - sigf(xi.x));
      if (ab4 & 1u) sa[kk] += e;
      if (vb4[i] & 1u) sv[kk] += e;
      e = fabsf(so4[i].y - sigf(xi.y));
      if (ab4 & 2u) sa[kk] += e;
      if (vb4[i] & 2u) sv[kk] += e;
      e = fabsf(so4[i].z - sigf(xi.z));
      if (ab4 & 4u) sa[kk] += e;
      if (vb4[i] & 4u) sv[kk] += e;
      e = fabsf(so4[i].w - sigf(xi.w));
      if (ab4 & 8u) sa[kk] += e;
      if (vb4[i] & 8u) sv[kk] += e;
    }
  };

  const int4* g1p = (const int4*)(gt + (size_t)(b * TV + t0[1] + w * 64) * TS) + lane;
  unsigned long long plane1 = 0ull;
  {
    float4 q0[4], q1[4];
    int4 P0[8], P1[8];
    issueP(q0, 0, 0);                          // pi group0 (tile0)
    if (t1v) {
#pragma unroll
      for (int q = 0; q < 8; ++q) P0[q] = g1p[q * 64];        // gt chunk0 (tile1)
    }
    // stage 0
    issueP(q1, 1, 0);
    if (t1v) {
#pragma unroll
      for (int q = 0; q < 8; ++q) P1[q] = g1p[(8 + q) * 64];  // chunk1
    }
    procBgrp(q0, 0, 0);
    if (t1v) {
#pragma unroll
      for (int q = 0; q < 8; ++q) procA(P0[q], 0 * 16 + 2 * q, plane1);
    }
    // stage 1
    issueP(q0, 2, 0);
    if (t1v) {
#pragma unroll
      for (int q = 0; q < 8; ++q) P0[q] = g1p[(16 + q) * 64]; // chunk2
    }
    procBgrp(q1, 1, 0);
    if (t1v) {
#pragma unroll
      for (int q = 0; q < 8; ++q) procA(P1[q], 1 * 16 + 2 * q, plane1);
    }
    // stage 2
    issueP(q1, 3, 0);
    if (t1v) {
#pragma unroll
      for (int q = 0; q < 8; ++q) P1[q] = g1p[(24 + q) * 64]; // chunk3
    }
    procBgrp(q0, 2, 0);
    if (t1v) {
#pragma unroll
      for (int q = 0; q < 8; ++q) procA(P0[q], 2 * 16 + 2 * q, plane1);
    }
    // stage 3
    procBgrp(q1, 3, 0);
    if (t1v) {
#pragma unroll
      for (int q = 0; q < 8; ++q) procA(P1[q], 3 * 16 + 2 * q, plane1);
    }
  }
  plane1 &= Vw[1];
  planes[1][w][lane] = t1v ? plane1 : 0ull;
  __syncthreads();

  // ---- tile1 B: pi depth-1 pipeline ----
  if (t1v) {
    float4 q0[4], q1[4];
    issueP(q0, 0, 1);
    issueP(q1, 1, 1);
    procBgrp(q0, 0, 1);
    issueP(q0, 2, 1);
    procBgrp(q1, 1, 1);
    issueP(q1, 3, 1);
    procBgrp(q0, 2, 1);
    procBgrp(q1, 3, 1);
  }

  // ---- epilogue (R4-proven): LDS slabs, 3 atomics per k ----
#pragma unroll
  for (int kk = 0; kk < 16; ++kk) {
    saL[16 * w + kk][lane] = sa[kk];
    svL[16 * w + kk][lane] = sv[kk];
  }
  __syncthreads();
  if (tid < KK) {
    const int k = tid;
    float SA = 0.f, SV = 0.f;
#pragma unroll 8
    for (int j = 0; j < 64; ++j) { SA += saL[k][j]; SV += svL[k][j]; }
    int ca = 0;
#pragma unroll
    for (int gg = 0; gg < 4; ++gg)
      ca += __popcll(planes[0][gg][k]) + __popcll(planes[1][gg][k]);
    atomicAdd(&gsa[k * BB + b], SA);
    atomicAdd(&gsv[k * BB + b], SV);
    if (ca) atomicAdd(&gca[k * BB + b], (float)ca);
  }
}

// ---------------------------------------------------------------------------
// Finalize: 1 block over the 2048 (k,b) pairs (logic verified R2-R8).
// ---------------------------------------------------------------------------
__global__ __launch_bounds__(256) void fin_kernel(
    const float* __restrict__ gsa, const float* __restrict__ gsv,
    const float* __restrict__ gca, const int* __restrict__ len,
    float* __restrict__ out) {
  float s = 0.f;
  for (int i = threadIdx.x; i < KK * BB; i += 256) {
    const int b = i & (BB - 1);
    const float ca = gca[i];
    const float cn = (float)len[b] - ca;
    if (ca > 0.f && cn > 0.f) {
      const float sa = gsa[i];
      const float sv = gsv[i];
      const float d = MARGIN_F - (sa / ca - (sv - sa) / cn);
      s += d > 0.f ? d : 0.f;
    }
  }
#pragma unroll
  for (int off = 32; off > 0; off >>= 1) s += __shfl_down(s, off);
  __shared__ float ws4[4];
  if ((threadIdx.x & 63) == 0) ws4[threadIdx.x >> 6] = s;
  __syncthreads();
  if (threadIdx.x == 0) {
    const float S = ws4[0] + ws4[1] + ws4[2] + ws4[3];
    const float ac = S * (1.0f / (float)(KK * BB));
    out[0] = ac;
    out[1] = ac * LAMBDA_F;
  }
}

extern "C" void kernel_launch(void* const* d_in, const int* in_sizes, int n_in,
                              void* d_out, int out_size, void* d_ws, size_t ws_size,
                              hipStream_t stream) {
  const float* pred_orig = (const float*)d_in[0];   // [B,TV] fp32
  const float* pred_int  = (const float*)d_in[1];   // [K,B,TV] fp32
  const int*   idx       = (const int*)d_in[2];     // [K] int32
  const int*   gt        = (const int*)d_in[3];     // [B,TV,TS] int32
  const int*   mv        = (const int*)d_in[4];     // [B,TV] int32
  float* out = (float*)d_out;

  float* gsa = (float*)d_ws;
  float* gsv = gsa + KK * BB;
  float* gca = gsv + KK * BB;
  int*   len = (int*)(gca + KK * BB);

  // zero the accumulator region (ws re-poisoned to 0xAA each call)
  hipMemsetAsync(d_ws, 0, (size_t)(3 * KK * BB) * sizeof(float) + BB * sizeof(int),
                 stream);
  fused_kernel<<<BB * NTILE / 2, 256, 0, stream>>>(
      pred_orig, pred_int, idx, gt, mv, gsa, gsv, gca, len);
  fin_kernel<<<1, 256, 0, stream>>>(gsa, gsv, gca, len, out);
}